// Round 6
// baseline (479.484 us; speedup 1.0000x reference)
//
#include <hip/hip_runtime.h>
#include <hip/hip_bf16.h>

// HCNet: L=4 hyper-connection blocks, N=4, D=2048, B*T=4096 tokens.
// R6: (1) gemm 512-thread / 8-wave (2x4 wave grid, 64x32 per wave) for 4
// waves/SIMD latency hiding; (2) fused_dw single-pass cross-term algebra:
// H' never materialized, Bv folded into apply coefficients.

#define DD 2048
#define NN 4
#define LL 4
#define NTOK 4096
#define EPSF 1e-5f

typedef __attribute__((ext_vector_type(8))) short bf16x8;
typedef __attribute__((ext_vector_type(4))) float f32x4;
typedef __attribute__((ext_vector_type(2))) float f32x2;

__device__ __forceinline__ float bf2f(short u) {
  union { unsigned int i; float f; } v;
  v.i = ((unsigned int)(unsigned short)u) << 16;
  return v.f;
}
__device__ __forceinline__ short f2bf(float f) {
  __hip_bfloat16 h = __float2bfloat16(f);
  short s;
  __builtin_memcpy(&s, &h, 2);
  return s;
}
__device__ __forceinline__ float wred(float v) {
#pragma unroll
  for (int off = 32; off > 0; off >>= 1) v += __shfl_xor(v, off, 64);
  return v;
}
__device__ __forceinline__ void ld16(const void* g, void* l) {
  __builtin_amdgcn_global_load_lds(
      (const __attribute__((address_space(1))) void*)g,
      (__attribute__((address_space(3))) void*)l, 16, 0, 0);
}

// ---------------- prep: gamma-scaled bf16 tables + beta/gamma ratio ---------
__global__ __launch_bounds__(256) void prep_pack(
    const float* __restrict__ W_m, const float* __restrict__ W_r,
    const float* __restrict__ W_b, const float* __restrict__ dyn_gamma,
    const float* __restrict__ norm_gamma, const float* __restrict__ norm_beta,
    short* __restrict__ gwm, short* __restrict__ gwr, short* __restrict__ gwb,
    float* __restrict__ rb) {
  const int i = blockIdx.x * 256 + threadIdx.x;  // over L*D = 8192
  const float g = dyn_gamma[i];
  gwm[i] = f2bf(g * W_m[i]);
  f32x4 r = *(const f32x4*)(W_r + (size_t)i * 4);
  f32x4 b = *(const f32x4*)(W_b + (size_t)i * 4);
  short ro[4], bo[4];
#pragma unroll
  for (int k = 0; k < 4; k++) { ro[k] = f2bf(g * r[k]); bo[k] = f2bf(g * b[k]); }
  *(unsigned long long*)(gwr + (size_t)i * 4) = *(unsigned long long*)ro;
  *(unsigned long long*)(gwb + (size_t)i * 4) = *(unsigned long long*)bo;
  rb[i] = norm_beta[i] / norm_gamma[i];
}

// ---------------- token-independent sums S0w[l][5], T0d[l][4] ---------------
__global__ __launch_bounds__(64) void prep_sums(
    const float* __restrict__ W_m, const float* __restrict__ W_r,
    const float* __restrict__ W_b, const float* __restrict__ dyn_gamma,
    float* __restrict__ S0w, float* __restrict__ T0d) {
  const int l = blockIdx.x;
  const int lane = threadIdx.x;
  float s[5] = {0, 0, 0, 0, 0}, t[4] = {0, 0, 0, 0};
  for (int d = lane; d < DD; d += 64) {
    const float g = dyn_gamma[l * DD + d];
    s[0] += g * W_m[l * DD + d];
    f32x4 r = *(const f32x4*)(W_r + ((size_t)l * DD + d) * 4);
    f32x4 b = *(const f32x4*)(W_b + ((size_t)l * DD + d) * 4);
#pragma unroll
    for (int m = 0; m < 4; m++) { s[1 + m] += g * r[m]; t[m] += g * b[m]; }
  }
#pragma unroll
  for (int m = 0; m < 5; m++) s[m] = wred(s[m]);
#pragma unroll
  for (int n = 0; n < 4; n++) t[n] = wred(t[n]);
  if (lane == 0) {
#pragma unroll
    for (int m = 0; m < 5; m++) S0w[l * 5 + m] = s[m];
#pragma unroll
    for (int n = 0; n < 4; n++) T0d[l * 4 + n] = t[n];
  }
}

// ------- transpose Wblk[l][d][e] (f32) -> Wt[l][e][d] = norm_g[d]*W (bf16) --
__global__ __launch_bounds__(256) void transpose_wblk(
    const float* __restrict__ W, const float* __restrict__ norm_gamma,
    short* __restrict__ Wt) {
  __shared__ float tile[64][65];
  const int blk = blockIdx.z;
  const int c0 = blockIdx.x * 64;
  const int r0 = blockIdx.y * 64;
  const float* Ws = W + (size_t)blk * DD * DD;
  short* Wd = Wt + (size_t)blk * DD * DD;
  const int tx = threadIdx.x & 63, ty = threadIdx.x >> 6;
#pragma unroll
  for (int r = 0; r < 16; r++) {
    const int row = ty + r * 4;
    tile[row][tx] = Ws[(size_t)(r0 + row) * DD + c0 + tx];
  }
  const float gsc = norm_gamma[blk * DD + r0 + tx];
  __syncthreads();
#pragma unroll
  for (int r = 0; r < 16; r++) {
    const int row = ty + r * 4;
    Wd[(size_t)(c0 + row) * DD + r0 + tx] = f2bf(tile[tx][row] * gsc);
  }
}

// ---------------- row sums of Wt': E1 = sum_d Wt', E0 = sum_d rb*Wt' + bias -
__global__ __launch_bounds__(256) void row_sums(
    const short* __restrict__ Wt, const float* __restrict__ rb,
    const float* __restrict__ bblk, float* __restrict__ E0,
    float* __restrict__ E1) {
  const int l = blockIdx.y;
  const int e = blockIdx.x * 4 + (threadIdx.x >> 6);
  const int lane = threadIdx.x & 63;
  const short* row = Wt + ((size_t)l * DD + e) * DD;
  const float* rbl = rb + l * DD;
  float s1 = 0.f, s0 = 0.f;
#pragma unroll
  for (int it = 0; it < 4; it++) {
    const int d0 = lane * 8 + it * 512;
    bf16x8 w = *(const bf16x8*)(row + d0);
    f32x4 r0 = *(const f32x4*)(rbl + d0), r1 = *(const f32x4*)(rbl + d0 + 4);
#pragma unroll
    for (int q = 0; q < 8; q++) {
      const float wq = bf2f(w[q]);
      s1 += wq;
      s0 += wq * ((q < 4) ? r0[q] : r1[q - 4]);
    }
  }
  s1 = wred(s1); s0 = wred(s0);
  if (lane == 0) {
    E1[l * DD + e] = s1;
    E0[l * DD + e] = s0 + bblk[l * DD + e];
  }
}

// ---------------- width connections, block 0 (reads x f32) ------------------
__global__ __launch_bounds__(256) void width0_kernel(
    const float* __restrict__ x, short* __restrict__ Hst,
    short* __restrict__ hout, f32x2* __restrict__ tst,
    const float* __restrict__ A_m, const float* __restrict__ A_r,
    const short* __restrict__ gwm, const short* __restrict__ gwr,
    const float* __restrict__ s_a, const float* __restrict__ S0w) {
  const int wave = threadIdx.x >> 6;
  const int lane = threadIdx.x & 63;
  const int tok = blockIdx.x * 4 + wave;
  const int blk = 0;
  const short* wm = gwm + blk * DD;
  const short* wr = gwr + (size_t)blk * DD * 4;

  bf16x8 hreg[4];  // all N rows identical at block 0
  const float* xr = x + (size_t)tok * DD;
#pragma unroll
  for (int j = 0; j < 4; j++) {
    const int d0 = lane * 8 + j * 512;
    f32x4 a = *(const f32x4*)(xr + d0);
    f32x4 b = *(const f32x4*)(xr + d0 + 4);
    bf16x8 p;
#pragma unroll
    for (int q = 0; q < 4; q++) { p[q] = f2bf(a[q]); p[4 + q] = f2bf(b[q]); }
    hreg[j] = p;
  }

  float sH = 0, sH2 = 0, S1[5] = {0, 0, 0, 0, 0};
#pragma unroll
  for (int j = 0; j < 4; j++) {
    const int d0 = lane * 8 + j * 512;
    bf16x8 mv = *(const bf16x8*)(wm + d0);
    bf16x8 wv[4];
#pragma unroll
    for (int p = 0; p < 4; p++)
      wv[p] = *(const bf16x8*)(wr + (size_t)(d0 + 2 * p) * 4);
#pragma unroll
    for (int q = 0; q < 8; q++) {
      const float hv = bf2f(hreg[j][q]);
      sH += hv; sH2 += hv * hv;
      S1[0] += hv * bf2f(mv[q]);
#pragma unroll
      for (int m = 0; m < 4; m++)
        S1[1 + m] += hv * bf2f(wv[q >> 1][(q & 1) * 4 + m]);
    }
  }
  sH = wred(sH); sH2 = wred(sH2);
#pragma unroll
  for (int m = 0; m < 5; m++) S1[m] = wred(S1[m]);

  const float sa = s_a[blk];
  const float mu0 = sH * (1.f / DD);
  const float inv0 = rsqrtf(sH2 * (1.f / DD) - mu0 * mu0 + EPSF);
  float amSum = 0.f, arCol[NN] = {0, 0, 0, 0};
  {
    const float t0 = tanhf(inv0 * (S1[0] - mu0 * S0w[blk * 5 + 0]));
    float tm[NN];
#pragma unroll
    for (int m = 0; m < NN; m++)
      tm[m] = tanhf(inv0 * (S1[1 + m] - mu0 * S0w[blk * 5 + 1 + m]));
#pragma unroll
    for (int n = 0; n < NN; n++) {
      amSum += A_m[blk * NN + n] + sa * t0;
#pragma unroll
      for (int m = 0; m < NN; m++)
        arCol[m] += A_r[blk * NN * NN + n * NN + m] + sa * tm[m];
    }
  }

  short* Ho = Hst + (size_t)tok * NN * DD;
  short* hw = hout + (size_t)tok * DD;
  float sh = 0.f, sh2 = 0.f;
#pragma unroll
  for (int j = 0; j < 4; j++) {
    const int d0 = lane * 8 + j * 512;
    bf16x8 outp[NN], ho;
#pragma unroll
    for (int q = 0; q < 8; q++) {
      const float hv = bf2f(hreg[j][q]);
      const float a0 = hv * amSum;
      sh += a0; sh2 += a0 * a0;
      ho[q] = f2bf(a0);
#pragma unroll
      for (int m = 0; m < NN; m++) outp[m][q] = f2bf(hv * arCol[m]);
    }
    *(bf16x8*)(hw + d0) = ho;
#pragma unroll
    for (int m = 0; m < NN; m++) *(bf16x8*)(Ho + m * DD + d0) = outp[m];
  }
  sh = wred(sh); sh2 = wred(sh2);
  if (lane == 0) {
    const float mu = sh * (1.f / DD);
    const float inv = rsqrtf(sh2 * (1.f / DD) - mu * mu + EPSF);
    f32x2 t; t[0] = inv; t[1] = mu * inv;
    tst[tok] = t;
  }
}

// ---------------- block GEMM: h2 = LN-folded(h @ Wt') -----------------------
// 512 threads, 8 waves (2 row-groups x 4 col-groups), each wave 64x32 out.
__global__ __launch_bounds__(512) void gemm_kernel(
    const short* __restrict__ A, const short* __restrict__ Bt,
    const f32x2* __restrict__ tst, const float* __restrict__ E0,
    const float* __restrict__ E1, short* __restrict__ C) {
  __shared__ short lA[2][128 * 64];
  __shared__ short lB[2][128 * 64];
  const int tid = threadIdx.x;
  const int lane = tid & 63;
  const int wave = tid >> 6;   // 0..7
  const int m0 = blockIdx.x * 128, n0 = blockIdx.y * 128;
  const int wm = wave >> 2;    // 0..1: 64-row group
  const int wn = wave & 3;     // 0..3: 32-col group

  f32x4 acc[4][2] = {};

#define STAGE(buf, kt)                                                        \
  {                                                                           \
    const int k0 = (kt) * 64;                                                 \
    _Pragma("unroll") for (int c = 0; c < 2; c++) {                           \
      const int idx = c * 512 + tid;                                          \
      const int row = idx >> 3;                                               \
      const int colsw = (((idx & 7) ^ (row & 7)) * 8);                        \
      ld16(A + (size_t)(m0 + row) * DD + k0 + colsw,                          \
           (char*)&lA[buf][0] + idx * 16);                                    \
      ld16(Bt + (size_t)(n0 + row) * DD + k0 + colsw,                         \
           (char*)&lB[buf][0] + idx * 16);                                    \
    }                                                                         \
  }

  STAGE(0, 0);
  __syncthreads();

  for (int kt = 0; kt < 32; ++kt) {
    const int cur = kt & 1;
    if (kt < 31) STAGE(cur ^ 1, kt + 1);
    const char* bufA = (const char*)&lA[cur][0];
    const char* bufB = (const char*)&lB[cur][0];
#pragma unroll
    for (int kk = 0; kk < 2; ++kk) {
      const int gsw = (kk * 64 + (lane >> 4) * 16) ^ ((lane & 7) << 4);
      bf16x8 af[4], bfr[2];
#pragma unroll
      for (int m = 0; m < 4; m++) {
        const int r = wm * 64 + m * 16 + (lane & 15);
        af[m] = *(const bf16x8*)(bufA + r * 128 + gsw);
      }
#pragma unroll
      for (int n = 0; n < 2; n++) {
        const int r = wn * 32 + n * 16 + (lane & 15);
        bfr[n] = *(const bf16x8*)(bufB + r * 128 + gsw);
      }
#pragma unroll
      for (int m = 0; m < 4; m++)
#pragma unroll
        for (int n = 0; n < 2; n++)
          acc[m][n] = __builtin_amdgcn_mfma_f32_16x16x32_bf16(
              af[m], bfr[n], acc[m][n], 0, 0, 0);
    }
    __syncthreads();
  }
#undef STAGE

  float e0c[2], e1c[2];
  int cols[2];
#pragma unroll
  for (int n = 0; n < 2; n++) {
    cols[n] = n0 + wn * 32 + n * 16 + (lane & 15);
    e0c[n] = E0[cols[n]];
    e1c[n] = E1[cols[n]];
  }
#pragma unroll
  for (int m = 0; m < 4; m++) {
    const int rbase = m0 + wm * 64 + m * 16 + ((lane >> 4) << 2);
#pragma unroll
    for (int j = 0; j < 4; j++) {
      const int row = rbase + j;
      const f32x2 iv = tst[row];
#pragma unroll
      for (int n = 0; n < 2; n++)
        C[(size_t)row * DD + cols[n]] =
            f2bf(iv[0] * acc[m][n][j] - iv[1] * e1c[n] + e0c[n]);
    }
  }
}

// ---------------- fused depth(blk) + width(blk+1), single-pass algebra ------
// H' = H + h2*Bv never materialized: cross-terms Cx/U1 give width stats,
// Bv folds into apply coefficients ca/cr.
__global__ __launch_bounds__(256) void fused_dw(
    const short* __restrict__ h2, short* __restrict__ Hst,
    short* __restrict__ hout, f32x2* __restrict__ tst,
    const float* __restrict__ Bp, const short* __restrict__ gwb,
    const float* __restrict__ s_b, const float* __restrict__ A_m,
    const float* __restrict__ A_r, const short* __restrict__ gwm,
    const short* __restrict__ gwr, const float* __restrict__ s_a,
    const float* __restrict__ S0w, const float* __restrict__ T0d, int blk) {
  const int wave = threadIdx.x >> 6;
  const int lane = threadIdx.x & 63;
  const int tok = blockIdx.x * 4 + wave;
  const int nblk = blk + 1;
  const short* hr = h2 + (size_t)tok * DD;
  short* Ho = Hst + (size_t)tok * NN * DD;

  // ---- issue all big loads early ----
  bf16x8 h2r[4], hold[NN][4];
#pragma unroll
  for (int j = 0; j < 4; j++) {
    const int d0 = lane * 8 + j * 512;
    h2r[j] = *(const bf16x8*)(hr + d0);
#pragma unroll
    for (int n = 0; n < NN; n++)
      hold[n][j] = *(const bf16x8*)(Ho + n * DD + d0);
  }

  const short* wb = gwb + (size_t)blk * DD * 4;    // depth table (blk)
  const short* wm = gwm + nblk * DD;               // width tables (nblk)
  const short* wr = gwr + (size_t)nblk * DD * 4;

  // ---- single stats pass ----
  float s1 = 0.f, s2 = 0.f;
  float T1[NN] = {0, 0, 0, 0}, U1[5] = {0, 0, 0, 0, 0}, Cx[NN] = {0, 0, 0, 0};
  float sH[NN] = {0, 0, 0, 0}, sH2[NN] = {0, 0, 0, 0};
  float S1[NN][5];
#pragma unroll
  for (int n = 0; n < NN; n++)
#pragma unroll
    for (int m = 0; m < 5; m++) S1[n][m] = 0.f;

#pragma unroll
  for (int j = 0; j < 4; j++) {
    const int d0 = lane * 8 + j * 512;
    bf16x8 mv = *(const bf16x8*)(wm + d0);
    bf16x8 wv[4], bv[4];
#pragma unroll
    for (int p = 0; p < 4; p++) {
      wv[p] = *(const bf16x8*)(wr + (size_t)(d0 + 2 * p) * 4);
      bv[p] = *(const bf16x8*)(wb + (size_t)(d0 + 2 * p) * 4);
    }
#pragma unroll
    for (int q = 0; q < 8; q++) {
      const float hv2 = bf2f(h2r[j][q]);
      s1 += hv2; s2 += hv2 * hv2;
      float gw[5];
      gw[0] = bf2f(mv[q]);
#pragma unroll
      for (int m = 0; m < 4; m++)
        gw[1 + m] = bf2f(wv[q >> 1][(q & 1) * 4 + m]);
#pragma unroll
      for (int n = 0; n < NN; n++)
        T1[n] += hv2 * bf2f(bv[q >> 1][(q & 1) * 4 + n]);
#pragma unroll
      for (int m = 0; m < 5; m++) U1[m] += hv2 * gw[m];
#pragma unroll
      for (int n = 0; n < NN; n++) {
        const float hvn = bf2f(hold[n][j][q]);
        Cx[n] += hvn * hv2;
        sH[n] += hvn; sH2[n] += hvn * hvn;
#pragma unroll
        for (int m = 0; m < 5; m++) S1[n][m] += hvn * gw[m];
      }
    }
  }
  s1 = wred(s1); s2 = wred(s2);
#pragma unroll
  for (int n = 0; n < NN; n++) {
    T1[n] = wred(T1[n]); Cx[n] = wred(Cx[n]);
    sH[n] = wred(sH[n]); sH2[n] = wred(sH2[n]);
  }
#pragma unroll
  for (int m = 0; m < 5; m++) U1[m] = wred(U1[m]);
#pragma unroll
  for (int n = 0; n < NN; n++)
#pragma unroll
    for (int m = 0; m < 5; m++) S1[n][m] = wred(S1[n][m]);

  // ---- depth coefficients ----
  float Bv[NN];
  {
    const float mu2 = s1 * (1.f / DD);
    const float inv2 = rsqrtf(s2 * (1.f / DD) - mu2 * mu2 + EPSF);
    const float sb = s_b[blk];
#pragma unroll
    for (int n = 0; n < NN; n++)
      Bv[n] = Bp[blk * NN + n] +
              sb * tanhf(inv2 * (T1[n] - mu2 * T0d[blk * NN + n]));
  }

  // ---- width coefficients from cross-term-expanded stats ----
  const float sa = s_a[nblk];
  float Am[NN], Ar[NN][NN];
#pragma unroll
  for (int n = 0; n < NN; n++) {
    const float sHp = sH[n] + Bv[n] * s1;
    const float sH2p = sH2[n] + 2.f * Bv[n] * Cx[n] + Bv[n] * Bv[n] * s2;
    const float mu = sHp * (1.f / DD);
    const float inv = rsqrtf(sH2p * (1.f / DD) - mu * mu + EPSF);
    const float S10 = S1[n][0] + Bv[n] * U1[0];
    Am[n] = A_m[nblk * NN + n] +
            sa * tanhf(inv * (S10 - mu * S0w[nblk * 5 + 0]));
#pragma unroll
    for (int m = 0; m < NN; m++) {
      const float S1m = S1[n][1 + m] + Bv[n] * U1[1 + m];
      Ar[n][m] = A_r[nblk * NN * NN + n * NN + m] +
                 sa * tanhf(inv * (S1m - mu * S0w[nblk * 5 + 1 + m]));
    }
  }
  float ca = 0.f, cr[NN] = {0, 0, 0, 0};
#pragma unroll
  for (int n = 0; n < NN; n++) {
    ca += Bv[n] * Am[n];
#pragma unroll
    for (int m = 0; m < NN; m++) cr[m] += Bv[n] * Ar[n][m];
  }

  // ---- apply: outputs directly from H and h2 ----
  short* hw = hout + (size_t)tok * DD;
  float sh = 0.f, sh2 = 0.f;
#pragma unroll
  for (int j = 0; j < 4; j++) {
    const int d0 = lane * 8 + j * 512;
    bf16x8 outp[NN], ho;
#pragma unroll
    for (int q = 0; q < 8; q++) {
      const float hv2 = bf2f(h2r[j][q]);
      float a0 = hv2 * ca;
      float am0 = hv2 * cr[0], am1 = hv2 * cr[1];
      float am2 = hv2 * cr[2], am3 = hv2 * cr[3];
#pragma unroll
      for (int n = 0; n < NN; n++) {
        const float hvn = bf2f(hold[n][j][q]);
        a0 += hvn * Am[n];
        am0 += hvn * Ar[n][0];
        am1 += hvn * Ar[n][1];
        am2 += hvn * Ar[n][2];
        am3 += hvn * Ar[n][3];
      }
      sh += a0; sh2 += a0 * a0;
      ho[q] = f2bf(a0);
      outp[0][q] = f2bf(am0); outp[1][q] = f2bf(am1);
      outp[2][q] = f2bf(am2); outp[3][q] = f2bf(am3);
    }
    *(bf16x8*)(hw + d0) = ho;
#pragma unroll
    for (int m = 0; m < NN; m++) *(bf16x8*)(Ho + m * DD + d0) = outp[m];
  }
  sh = wred(sh); sh2 = wred(sh2);
  if (lane == 0) {
    const float mu = sh * (1.f / DD);
    const float inv = rsqrtf(sh2 * (1.f / DD) - mu * mu + EPSF);
    f32x2 t; t[0] = inv; t[1] = mu * inv;
    tst[tok] = t;
  }
}

// ---------------- final depth (block 3) + output sum ------------------------
__global__ __launch_bounds__(256) void depth_last(
    const short* __restrict__ h2, const short* __restrict__ Hst,
    float* __restrict__ out, const float* __restrict__ Bp,
    const short* __restrict__ gwb, const float* __restrict__ s_b,
    const float* __restrict__ T0d, int blk) {
  const int wave = threadIdx.x >> 6;
  const int lane = threadIdx.x & 63;
  const int tok = blockIdx.x * 4 + wave;
  const short* hr = h2 + (size_t)tok * DD;
  const short* wb = gwb + (size_t)blk * DD * 4;

  bf16x8 h2r[4];
  float s1 = 0.f, s2 = 0.f, T1[NN] = {0, 0, 0, 0};
#pragma unroll
  for (int j = 0; j < 4; j++) {
    const int d0 = lane * 8 + j * 512;
    h2r[j] = *(const bf16x8*)(hr + d0);
    bf16x8 wv[4];
#pragma unroll
    for (int p = 0; p < 4; p++)
      wv[p] = *(const bf16x8*)(wb + (size_t)(d0 + 2 * p) * 4);
#pragma unroll
    for (int q = 0; q < 8; q++) {
      const float hv = bf2f(h2r[j][q]);
      s1 += hv; s2 += hv * hv;
#pragma unroll
      for (int n = 0; n < NN; n++)
        T1[n] += hv * bf2f(wv[q >> 1][(q & 1) * 4 + n]);
    }
  }
  s1 = wred(s1); s2 = wred(s2);
#pragma unroll
  for (int n = 0; n < NN; n++) T1[n] = wred(T1[n]);
  const float mu = s1 * (1.f / DD);
  const float inv = rsqrtf(s2 * (1.f / DD) - mu * mu + EPSF);
  const float sb = s_b[blk];
  float bsum = 0.f;
#pragma unroll
  for (int n = 0; n < NN; n++)
    bsum += Bp[blk * NN + n] + sb * tanhf(inv * (T1[n] - mu * T0d[blk * NN + n]));

  const short* Ho = Hst + (size_t)tok * NN * DD;
  float* orow = out + (size_t)tok * DD;
#pragma unroll
  for (int j = 0; j < 4; j++) {
    const int d0 = lane * 8 + j * 512;
    bf16x8 hrow[NN];
#pragma unroll
    for (int n = 0; n < NN; n++) hrow[n] = *(const bf16x8*)(Ho + n * DD + d0);
    f32x4 o0, o1;
#pragma unroll
    for (int q = 0; q < 8; q++) {
      const float hv = bf2f(h2r[j][q]);
      float s = hv * bsum;
#pragma unroll
      for (int n = 0; n < NN; n++) s += bf2f(hrow[n][q]);
      if (q < 4) o0[q] = s; else o1[q - 4] = s;
    }
    *(f32x4*)(orow + d0) = o0;
    *(f32x4*)(orow + d0 + 4) = o1;
  }
}

extern "C" void kernel_launch(void* const* d_in, const int* in_sizes, int n_in,
                              void* d_out, int out_size, void* d_ws,
                              size_t ws_size, hipStream_t stream) {
  const float* x = (const float*)d_in[0];
  const float* A_m = (const float*)d_in[1];
  const float* A_r = (const float*)d_in[2];
  const float* Bp = (const float*)d_in[3];
  const float* W_m = (const float*)d_in[4];
  const float* W_r = (const float*)d_in[5];
  const float* W_b = (const float*)d_in[6];
  const float* s_a = (const float*)d_in[7];
  const float* s_b = (const float*)d_in[8];
  const float* dyn_gamma = (const float*)d_in[9];
  const float* norm_gamma = (const float*)d_in[10];
  const float* norm_beta = (const float*)d_in[11];
  const float* Wblk = (const float*)d_in[12];
  const float* bblk = (const float*)d_in[13];
  float* out = (float*)d_out;

  char* ws = (char*)d_ws;
  short* Hst = (short*)(ws);                      // [0, 64 MiB)
  short* hbuf = (short*)(ws + 67108864);          // [64, 80) unnormalized h
  short* h2 = (short*)(ws + 83886080);            // [80, 96)
  char* aux = ws + 100663296;                     // [96 MiB, ...)
  short* gwm = (short*)(aux);                     // 16 KiB
  short* gwr = (short*)(aux + 16384);             // 64 KiB
  short* gwb = (short*)(aux + 16384 + 65536);     // 64 KiB
  float* rb = (float*)(aux + 16384 + 131072);     // 32 KiB
  float* S0w = (float*)(aux + 16384 + 131072 + 32768);
  float* T0d = (float*)(aux + 16384 + 131072 + 32768 + 128);
  f32x2* tst = (f32x2*)(aux + 16384 + 131072 + 32768 + 256);  // 32 KiB
  float* E0 = (float*)(aux + 16384 + 131072 + 32768 + 256 + 32768);  // 32 KiB
  float* E1 = E0 + LL * DD;                                          // 32 KiB
  // Wt lives in d_out: recomputed every call, overwritten by depth_last
  short* Wt = (short*)d_out;

  dim3 tb(256);
  prep_pack<<<32, tb, 0, stream>>>(W_m, W_r, W_b, dyn_gamma, norm_gamma,
                                   norm_beta, gwm, gwr, gwb, rb);
  prep_sums<<<4, dim3(64), 0, stream>>>(W_m, W_r, W_b, dyn_gamma, S0w, T0d);
  transpose_wblk<<<dim3(32, 32, 4), tb, 0, stream>>>(Wblk, norm_gamma, Wt);
  row_sums<<<dim3(512, 4), tb, 0, stream>>>(Wt, rb, bblk, E0, E1);
  width0_kernel<<<1024, tb, 0, stream>>>(x, Hst, hbuf, tst, A_m, A_r, gwm,
                                         gwr, s_a, S0w);
  for (int i = 0; i < LL; i++) {
    gemm_kernel<<<dim3(32, 16), dim3(512), 0, stream>>>(
        hbuf, Wt + (size_t)i * DD * DD, tst, E0 + i * DD, E1 + i * DD, h2);
    if (i < LL - 1)
      fused_dw<<<1024, tb, 0, stream>>>(h2, Hst, hbuf, tst, Bp, gwb, s_b, A_m,
                                        A_r, gwm, gwr, s_a, S0w, T0d, i);
    else
      depth_last<<<1024, tb, 0, stream>>>(h2, Hst, out, Bp, gwb, s_b, T0d, i);
  }
}

// Round 7
// 369.125 us; speedup vs baseline: 1.2990x; 1.2990x over previous
//
#include <hip/hip_runtime.h>
#include <hip/hip_bf16.h>

// HCNet: L=4 hyper-connection blocks, N=4, D=2048, B*T=4096 tokens.
// R7: fused_dw = R5 two-pass skeleton but H streamed per-j (no hold[16] live
// across phases; H' computed on the fly, apply re-loads H from L2/L3) ->
// VGPR ~100. gemm keeps R6 8-wave shape + XCD-aware block swizzle.

#define DD 2048
#define NN 4
#define LL 4
#define NTOK 4096
#define EPSF 1e-5f

typedef __attribute__((ext_vector_type(8))) short bf16x8;
typedef __attribute__((ext_vector_type(4))) float f32x4;
typedef __attribute__((ext_vector_type(2))) float f32x2;

__device__ __forceinline__ float bf2f(short u) {
  union { unsigned int i; float f; } v;
  v.i = ((unsigned int)(unsigned short)u) << 16;
  return v.f;
}
__device__ __forceinline__ short f2bf(float f) {
  __hip_bfloat16 h = __float2bfloat16(f);
  short s;
  __builtin_memcpy(&s, &h, 2);
  return s;
}
__device__ __forceinline__ float wred(float v) {
#pragma unroll
  for (int off = 32; off > 0; off >>= 1) v += __shfl_xor(v, off, 64);
  return v;
}
__device__ __forceinline__ void ld16(const void* g, void* l) {
  __builtin_amdgcn_global_load_lds(
      (const __attribute__((address_space(1))) void*)g,
      (__attribute__((address_space(3))) void*)l, 16, 0, 0);
}

// ---------------- prep: gamma-scaled bf16 tables + beta/gamma ratio ---------
__global__ __launch_bounds__(256) void prep_pack(
    const float* __restrict__ W_m, const float* __restrict__ W_r,
    const float* __restrict__ W_b, const float* __restrict__ dyn_gamma,
    const float* __restrict__ norm_gamma, const float* __restrict__ norm_beta,
    short* __restrict__ gwm, short* __restrict__ gwr, short* __restrict__ gwb,
    float* __restrict__ rb) {
  const int i = blockIdx.x * 256 + threadIdx.x;  // over L*D = 8192
  const float g = dyn_gamma[i];
  gwm[i] = f2bf(g * W_m[i]);
  f32x4 r = *(const f32x4*)(W_r + (size_t)i * 4);
  f32x4 b = *(const f32x4*)(W_b + (size_t)i * 4);
  short ro[4], bo[4];
#pragma unroll
  for (int k = 0; k < 4; k++) { ro[k] = f2bf(g * r[k]); bo[k] = f2bf(g * b[k]); }
  *(unsigned long long*)(gwr + (size_t)i * 4) = *(unsigned long long*)ro;
  *(unsigned long long*)(gwb + (size_t)i * 4) = *(unsigned long long*)bo;
  rb[i] = norm_beta[i] / norm_gamma[i];
}

// ---------------- token-independent sums S0w[l][5], T0d[l][4] ---------------
__global__ __launch_bounds__(64) void prep_sums(
    const float* __restrict__ W_m, const float* __restrict__ W_r,
    const float* __restrict__ W_b, const float* __restrict__ dyn_gamma,
    float* __restrict__ S0w, float* __restrict__ T0d) {
  const int l = blockIdx.x;
  const int lane = threadIdx.x;
  float s[5] = {0, 0, 0, 0, 0}, t[4] = {0, 0, 0, 0};
  for (int d = lane; d < DD; d += 64) {
    const float g = dyn_gamma[l * DD + d];
    s[0] += g * W_m[l * DD + d];
    f32x4 r = *(const f32x4*)(W_r + ((size_t)l * DD + d) * 4);
    f32x4 b = *(const f32x4*)(W_b + ((size_t)l * DD + d) * 4);
#pragma unroll
    for (int m = 0; m < 4; m++) { s[1 + m] += g * r[m]; t[m] += g * b[m]; }
  }
#pragma unroll
  for (int m = 0; m < 5; m++) s[m] = wred(s[m]);
#pragma unroll
  for (int n = 0; n < 4; n++) t[n] = wred(t[n]);
  if (lane == 0) {
#pragma unroll
    for (int m = 0; m < 5; m++) S0w[l * 5 + m] = s[m];
#pragma unroll
    for (int n = 0; n < 4; n++) T0d[l * 4 + n] = t[n];
  }
}

// ------- transpose Wblk[l][d][e] (f32) -> Wt[l][e][d] = norm_g[d]*W (bf16) --
__global__ __launch_bounds__(256) void transpose_wblk(
    const float* __restrict__ W, const float* __restrict__ norm_gamma,
    short* __restrict__ Wt) {
  __shared__ float tile[64][65];
  const int blk = blockIdx.z;
  const int c0 = blockIdx.x * 64;
  const int r0 = blockIdx.y * 64;
  const float* Ws = W + (size_t)blk * DD * DD;
  short* Wd = Wt + (size_t)blk * DD * DD;
  const int tx = threadIdx.x & 63, ty = threadIdx.x >> 6;
#pragma unroll
  for (int r = 0; r < 16; r++) {
    const int row = ty + r * 4;
    tile[row][tx] = Ws[(size_t)(r0 + row) * DD + c0 + tx];
  }
  const float gsc = norm_gamma[blk * DD + r0 + tx];
  __syncthreads();
#pragma unroll
  for (int r = 0; r < 16; r++) {
    const int row = ty + r * 4;
    Wd[(size_t)(c0 + row) * DD + r0 + tx] = f2bf(tile[tx][row] * gsc);
  }
}

// ---------------- row sums of Wt': E1 = sum_d Wt', E0 = sum_d rb*Wt' + bias -
__global__ __launch_bounds__(256) void row_sums(
    const short* __restrict__ Wt, const float* __restrict__ rb,
    const float* __restrict__ bblk, float* __restrict__ E0,
    float* __restrict__ E1) {
  const int l = blockIdx.y;
  const int e = blockIdx.x * 4 + (threadIdx.x >> 6);
  const int lane = threadIdx.x & 63;
  const short* row = Wt + ((size_t)l * DD + e) * DD;
  const float* rbl = rb + l * DD;
  float s1 = 0.f, s0 = 0.f;
#pragma unroll
  for (int it = 0; it < 4; it++) {
    const int d0 = lane * 8 + it * 512;
    bf16x8 w = *(const bf16x8*)(row + d0);
    f32x4 r0 = *(const f32x4*)(rbl + d0), r1 = *(const f32x4*)(rbl + d0 + 4);
#pragma unroll
    for (int q = 0; q < 8; q++) {
      const float wq = bf2f(w[q]);
      s1 += wq;
      s0 += wq * ((q < 4) ? r0[q] : r1[q - 4]);
    }
  }
  s1 = wred(s1); s0 = wred(s0);
  if (lane == 0) {
    E1[l * DD + e] = s1;
    E0[l * DD + e] = s0 + bblk[l * DD + e];
  }
}

// ---------------- width connections, block 0 (reads x f32) ------------------
__global__ __launch_bounds__(256) void width0_kernel(
    const float* __restrict__ x, short* __restrict__ Hst,
    short* __restrict__ hout, f32x2* __restrict__ tst,
    const float* __restrict__ A_m, const float* __restrict__ A_r,
    const short* __restrict__ gwm, const short* __restrict__ gwr,
    const float* __restrict__ s_a, const float* __restrict__ S0w) {
  const int wave = threadIdx.x >> 6;
  const int lane = threadIdx.x & 63;
  const int tok = blockIdx.x * 4 + wave;
  const int blk = 0;
  const short* wm = gwm + blk * DD;
  const short* wr = gwr + (size_t)blk * DD * 4;

  bf16x8 hreg[4];  // all N rows identical at block 0
  const float* xr = x + (size_t)tok * DD;
#pragma unroll
  for (int j = 0; j < 4; j++) {
    const int d0 = lane * 8 + j * 512;
    f32x4 a = *(const f32x4*)(xr + d0);
    f32x4 b = *(const f32x4*)(xr + d0 + 4);
    bf16x8 p;
#pragma unroll
    for (int q = 0; q < 4; q++) { p[q] = f2bf(a[q]); p[4 + q] = f2bf(b[q]); }
    hreg[j] = p;
  }

  float sH = 0, sH2 = 0, S1[5] = {0, 0, 0, 0, 0};
#pragma unroll
  for (int j = 0; j < 4; j++) {
    const int d0 = lane * 8 + j * 512;
    bf16x8 mv = *(const bf16x8*)(wm + d0);
    bf16x8 wv[4];
#pragma unroll
    for (int p = 0; p < 4; p++)
      wv[p] = *(const bf16x8*)(wr + (size_t)(d0 + 2 * p) * 4);
#pragma unroll
    for (int q = 0; q < 8; q++) {
      const float hv = bf2f(hreg[j][q]);
      sH += hv; sH2 += hv * hv;
      S1[0] += hv * bf2f(mv[q]);
#pragma unroll
      for (int m = 0; m < 4; m++)
        S1[1 + m] += hv * bf2f(wv[q >> 1][(q & 1) * 4 + m]);
    }
  }
  sH = wred(sH); sH2 = wred(sH2);
#pragma unroll
  for (int m = 0; m < 5; m++) S1[m] = wred(S1[m]);

  const float sa = s_a[blk];
  const float mu0 = sH * (1.f / DD);
  const float inv0 = rsqrtf(sH2 * (1.f / DD) - mu0 * mu0 + EPSF);
  float amSum = 0.f, arCol[NN] = {0, 0, 0, 0};
  {
    const float t0 = tanhf(inv0 * (S1[0] - mu0 * S0w[blk * 5 + 0]));
    float tm[NN];
#pragma unroll
    for (int m = 0; m < NN; m++)
      tm[m] = tanhf(inv0 * (S1[1 + m] - mu0 * S0w[blk * 5 + 1 + m]));
#pragma unroll
    for (int n = 0; n < NN; n++) {
      amSum += A_m[blk * NN + n] + sa * t0;
#pragma unroll
      for (int m = 0; m < NN; m++)
        arCol[m] += A_r[blk * NN * NN + n * NN + m] + sa * tm[m];
    }
  }

  short* Ho = Hst + (size_t)tok * NN * DD;
  short* hw = hout + (size_t)tok * DD;
  float sh = 0.f, sh2 = 0.f;
#pragma unroll
  for (int j = 0; j < 4; j++) {
    const int d0 = lane * 8 + j * 512;
    bf16x8 outp[NN], ho;
#pragma unroll
    for (int q = 0; q < 8; q++) {
      const float hv = bf2f(hreg[j][q]);
      const float a0 = hv * amSum;
      sh += a0; sh2 += a0 * a0;
      ho[q] = f2bf(a0);
#pragma unroll
      for (int m = 0; m < NN; m++) outp[m][q] = f2bf(hv * arCol[m]);
    }
    *(bf16x8*)(hw + d0) = ho;
#pragma unroll
    for (int m = 0; m < NN; m++) *(bf16x8*)(Ho + m * DD + d0) = outp[m];
  }
  sh = wred(sh); sh2 = wred(sh2);
  if (lane == 0) {
    const float mu = sh * (1.f / DD);
    const float inv = rsqrtf(sh2 * (1.f / DD) - mu * mu + EPSF);
    f32x2 t; t[0] = inv; t[1] = mu * inv;
    tst[tok] = t;
  }
}

// ---------------- block GEMM: h2 = LN-folded(h @ Wt') -----------------------
// 512 threads, 8 waves (2 row-groups x 4 col-groups), XCD-swizzled 1D grid.
__global__ __launch_bounds__(512) void gemm_kernel(
    const short* __restrict__ A, const short* __restrict__ Bt,
    const f32x2* __restrict__ tst, const float* __restrict__ E0,
    const float* __restrict__ E1, short* __restrict__ C) {
  __shared__ short lA[2][128 * 64];
  __shared__ short lB[2][128 * 64];
  const int tid = threadIdx.x;
  const int lane = tid & 63;
  const int wave = tid >> 6;   // 0..7
  // XCD swizzle: 512 wgs, 8 XCDs -> each XCD gets 64 consecutive work units
  // = 2 full B-panels (32 m-tiles each) -> B-tile L2 reuse within XCD.
  const int bid = blockIdx.x;
  const int wg = (bid & 7) * 64 + (bid >> 3);
  const int m0 = (wg & 31) * 128, n0 = (wg >> 5) * 128;
  const int wm = wave >> 2;    // 0..1: 64-row group
  const int wn = wave & 3;     // 0..3: 32-col group

  f32x4 acc[4][2] = {};

#define STAGE(buf, kt)                                                        \
  {                                                                           \
    const int k0 = (kt) * 64;                                                 \
    _Pragma("unroll") for (int c = 0; c < 2; c++) {                           \
      const int idx = c * 512 + tid;                                          \
      const int row = idx >> 3;                                               \
      const int colsw = (((idx & 7) ^ (row & 7)) * 8);                        \
      ld16(A + (size_t)(m0 + row) * DD + k0 + colsw,                          \
           (char*)&lA[buf][0] + idx * 16);                                    \
      ld16(Bt + (size_t)(n0 + row) * DD + k0 + colsw,                         \
           (char*)&lB[buf][0] + idx * 16);                                    \
    }                                                                         \
  }

  STAGE(0, 0);
  __syncthreads();

  for (int kt = 0; kt < 32; ++kt) {
    const int cur = kt & 1;
    if (kt < 31) STAGE(cur ^ 1, kt + 1);
    const char* bufA = (const char*)&lA[cur][0];
    const char* bufB = (const char*)&lB[cur][0];
#pragma unroll
    for (int kk = 0; kk < 2; ++kk) {
      const int gsw = (kk * 64 + (lane >> 4) * 16) ^ ((lane & 7) << 4);
      bf16x8 af[4], bfr[2];
#pragma unroll
      for (int m = 0; m < 4; m++) {
        const int r = wm * 64 + m * 16 + (lane & 15);
        af[m] = *(const bf16x8*)(bufA + r * 128 + gsw);
      }
#pragma unroll
      for (int n = 0; n < 2; n++) {
        const int r = wn * 32 + n * 16 + (lane & 15);
        bfr[n] = *(const bf16x8*)(bufB + r * 128 + gsw);
      }
#pragma unroll
      for (int m = 0; m < 4; m++)
#pragma unroll
        for (int n = 0; n < 2; n++)
          acc[m][n] = __builtin_amdgcn_mfma_f32_16x16x32_bf16(
              af[m], bfr[n], acc[m][n], 0, 0, 0);
    }
    __syncthreads();
  }
#undef STAGE

  float e0c[2], e1c[2];
  int cols[2];
#pragma unroll
  for (int n = 0; n < 2; n++) {
    cols[n] = n0 + wn * 32 + n * 16 + (lane & 15);
    e0c[n] = E0[cols[n]];
    e1c[n] = E1[cols[n]];
  }
#pragma unroll
  for (int m = 0; m < 4; m++) {
    const int rbase = m0 + wm * 64 + m * 16 + ((lane >> 4) << 2);
#pragma unroll
    for (int j = 0; j < 4; j++) {
      const int row = rbase + j;
      const f32x2 iv = tst[row];
#pragma unroll
      for (int n = 0; n < 2; n++)
        C[(size_t)row * DD + cols[n]] =
            f2bf(iv[0] * acc[m][n][j] - iv[1] * e1c[n] + e0c[n]);
    }
  }
}

// ---------------- fused depth(blk) + width(blk+1), streamed-H ---------------
// Two sequential reduction phases (Bv first), H' = H + h2*Bv computed on the
// fly; H streamed per-j in both width-stats and apply (re-read from L2/L3).
__global__ __launch_bounds__(256) void fused_dw(
    const short* __restrict__ h2, short* __restrict__ Hst,
    short* __restrict__ hout, f32x2* __restrict__ tst,
    const float* __restrict__ Bp, const short* __restrict__ gwb,
    const float* __restrict__ s_b, const float* __restrict__ A_m,
    const float* __restrict__ A_r, const short* __restrict__ gwm,
    const short* __restrict__ gwr, const float* __restrict__ s_a,
    const float* __restrict__ S0w, const float* __restrict__ T0d, int blk) {
  const int wave = threadIdx.x >> 6;
  const int lane = threadIdx.x & 63;
  const int tok = blockIdx.x * 4 + wave;
  const int nblk = blk + 1;
  const short* hr = h2 + (size_t)tok * DD;
  short* Ho = Hst + (size_t)tok * NN * DD;

  bf16x8 h2r[4];
#pragma unroll
  for (int j = 0; j < 4; j++)
    h2r[j] = *(const bf16x8*)(hr + lane * 8 + j * 512);

  // ---- phase A: depth stats on h2 ----
  const short* wb = gwb + (size_t)blk * DD * 4;
  float s1 = 0.f, s2 = 0.f, T1[NN] = {0, 0, 0, 0};
#pragma unroll
  for (int j = 0; j < 4; j++) {
    const int d0 = lane * 8 + j * 512;
    bf16x8 wv[4];
#pragma unroll
    for (int p = 0; p < 4; p++)
      wv[p] = *(const bf16x8*)(wb + (size_t)(d0 + 2 * p) * 4);
#pragma unroll
    for (int q = 0; q < 8; q++) {
      const float hv = bf2f(h2r[j][q]);
      s1 += hv; s2 += hv * hv;
#pragma unroll
      for (int n = 0; n < NN; n++)
        T1[n] += hv * bf2f(wv[q >> 1][(q & 1) * 4 + n]);
    }
  }
  s1 = wred(s1); s2 = wred(s2);
#pragma unroll
  for (int n = 0; n < NN; n++) T1[n] = wred(T1[n]);
  float Bv[NN];
  {
    const float mu = s1 * (1.f / DD);
    const float inv = rsqrtf(s2 * (1.f / DD) - mu * mu + EPSF);
    const float sb = s_b[blk];
#pragma unroll
    for (int n = 0; n < NN; n++)
      Bv[n] = Bp[blk * NN + n] +
              sb * tanhf(inv * (T1[n] - mu * T0d[blk * NN + n]));
  }

  // ---- phase B: width stats on H' (H streamed, H' on the fly) ----
  const short* wm = gwm + nblk * DD;
  const short* wr = gwr + (size_t)nblk * DD * 4;
  float sH[NN] = {0, 0, 0, 0}, sH2[NN] = {0, 0, 0, 0};
  float S1[NN][5];
#pragma unroll
  for (int n = 0; n < NN; n++)
#pragma unroll
    for (int m = 0; m < 5; m++) S1[n][m] = 0.f;

#pragma unroll
  for (int j = 0; j < 4; j++) {
    const int d0 = lane * 8 + j * 512;
    bf16x8 hold[NN];
#pragma unroll
    for (int n = 0; n < NN; n++) hold[n] = *(const bf16x8*)(Ho + n * DD + d0);
    bf16x8 mv = *(const bf16x8*)(wm + d0);
    bf16x8 wv[4];
#pragma unroll
    for (int p = 0; p < 4; p++)
      wv[p] = *(const bf16x8*)(wr + (size_t)(d0 + 2 * p) * 4);
#pragma unroll
    for (int q = 0; q < 8; q++) {
      const float hv2 = bf2f(h2r[j][q]);
      float gw[5];
      gw[0] = bf2f(mv[q]);
#pragma unroll
      for (int m = 0; m < 4; m++)
        gw[1 + m] = bf2f(wv[q >> 1][(q & 1) * 4 + m]);
#pragma unroll
      for (int n = 0; n < NN; n++) {
        const float hp = bf2f(hold[n][q]) + hv2 * Bv[n];
        sH[n] += hp; sH2[n] += hp * hp;
#pragma unroll
        for (int m = 0; m < 5; m++) S1[n][m] += hp * gw[m];
      }
    }
  }
#pragma unroll
  for (int n = 0; n < NN; n++) { sH[n] = wred(sH[n]); sH2[n] = wred(sH2[n]); }
#pragma unroll
  for (int n = 0; n < NN; n++)
#pragma unroll
    for (int m = 0; m < 5; m++) S1[n][m] = wred(S1[n][m]);

  const float sa = s_a[nblk];
  float Am[NN], Ar[NN][NN];
#pragma unroll
  for (int n = 0; n < NN; n++) {
    const float mu = sH[n] * (1.f / DD);
    const float var = sH2[n] * (1.f / DD) - mu * mu;
    const float inv = rsqrtf(var + EPSF);
    Am[n] = A_m[nblk * NN + n] +
            sa * tanhf(inv * (S1[n][0] - mu * S0w[nblk * 5 + 0]));
#pragma unroll
    for (int m = 0; m < NN; m++)
      Ar[n][m] = A_r[nblk * NN * NN + n * NN + m] +
                 sa * tanhf(inv * (S1[n][1 + m] - mu * S0w[nblk * 5 + 1 + m]));
  }

  // ---- phase C: apply (H re-streamed, H' recomputed) ----
  short* hw = hout + (size_t)tok * DD;
  float sh = 0.f, sh2 = 0.f;
#pragma unroll
  for (int j = 0; j < 4; j++) {
    const int d0 = lane * 8 + j * 512;
    bf16x8 hold[NN];
#pragma unroll
    for (int n = 0; n < NN; n++) hold[n] = *(const bf16x8*)(Ho + n * DD + d0);
    bf16x8 outp[NN], ho;
#pragma unroll
    for (int q = 0; q < 8; q++) {
      const float hv2 = bf2f(h2r[j][q]);
      float hp[NN];
#pragma unroll
      for (int n = 0; n < NN; n++) hp[n] = bf2f(hold[n][q]) + hv2 * Bv[n];
      float a0 = 0.f, am0 = 0.f, am1 = 0.f, am2 = 0.f, am3 = 0.f;
#pragma unroll
      for (int n = 0; n < NN; n++) {
        a0 += hp[n] * Am[n];
        am0 += hp[n] * Ar[n][0];
        am1 += hp[n] * Ar[n][1];
        am2 += hp[n] * Ar[n][2];
        am3 += hp[n] * Ar[n][3];
      }
      sh += a0; sh2 += a0 * a0;
      ho[q] = f2bf(a0);
      outp[0][q] = f2bf(am0); outp[1][q] = f2bf(am1);
      outp[2][q] = f2bf(am2); outp[3][q] = f2bf(am3);
    }
    *(bf16x8*)(hw + d0) = ho;
#pragma unroll
    for (int m = 0; m < NN; m++) *(bf16x8*)(Ho + m * DD + d0) = outp[m];
  }
  sh = wred(sh); sh2 = wred(sh2);
  if (lane == 0) {
    const float mu = sh * (1.f / DD);
    const float inv = rsqrtf(sh2 * (1.f / DD) - mu * mu + EPSF);
    f32x2 t; t[0] = inv; t[1] = mu * inv;
    tst[tok] = t;
  }
}

// ---------------- final depth (block 3) + output sum ------------------------
__global__ __launch_bounds__(256) void depth_last(
    const short* __restrict__ h2, const short* __restrict__ Hst,
    float* __restrict__ out, const float* __restrict__ Bp,
    const short* __restrict__ gwb, const float* __restrict__ s_b,
    const float* __restrict__ T0d, int blk) {
  const int wave = threadIdx.x >> 6;
  const int lane = threadIdx.x & 63;
  const int tok = blockIdx.x * 4 + wave;
  const short* hr = h2 + (size_t)tok * DD;
  const short* wb = gwb + (size_t)blk * DD * 4;

  bf16x8 h2r[4];
  float s1 = 0.f, s2 = 0.f, T1[NN] = {0, 0, 0, 0};
#pragma unroll
  for (int j = 0; j < 4; j++) {
    const int d0 = lane * 8 + j * 512;
    h2r[j] = *(const bf16x8*)(hr + d0);
    bf16x8 wv[4];
#pragma unroll
    for (int p = 0; p < 4; p++)
      wv[p] = *(const bf16x8*)(wb + (size_t)(d0 + 2 * p) * 4);
#pragma unroll
    for (int q = 0; q < 8; q++) {
      const float hv = bf2f(h2r[j][q]);
      s1 += hv; s2 += hv * hv;
#pragma unroll
      for (int n = 0; n < NN; n++)
        T1[n] += hv * bf2f(wv[q >> 1][(q & 1) * 4 + n]);
    }
  }
  s1 = wred(s1); s2 = wred(s2);
#pragma unroll
  for (int n = 0; n < NN; n++) T1[n] = wred(T1[n]);
  const float mu = s1 * (1.f / DD);
  const float inv = rsqrtf(s2 * (1.f / DD) - mu * mu + EPSF);
  const float sb = s_b[blk];
  float bsum = 0.f;
#pragma unroll
  for (int n = 0; n < NN; n++)
    bsum += Bp[blk * NN + n] + sb * tanhf(inv * (T1[n] - mu * T0d[blk * NN + n]));

  const short* Ho = Hst + (size_t)tok * NN * DD;
  float* orow = out + (size_t)tok * DD;
#pragma unroll
  for (int j = 0; j < 4; j++) {
    const int d0 = lane * 8 + j * 512;
    bf16x8 hrow[NN];
#pragma unroll
    for (int n = 0; n < NN; n++) hrow[n] = *(const bf16x8*)(Ho + n * DD + d0);
    f32x4 o0, o1;
#pragma unroll
    for (int q = 0; q < 8; q++) {
      const float hv = bf2f(h2r[j][q]);
      float s = hv * bsum;
#pragma unroll
      for (int n = 0; n < NN; n++) s += bf2f(hrow[n][q]);
      if (q < 4) o0[q] = s; else o1[q - 4] = s;
    }
    *(f32x4*)(orow + d0) = o0;
    *(f32x4*)(orow + d0 + 4) = o1;
  }
}

extern "C" void kernel_launch(void* const* d_in, const int* in_sizes, int n_in,
                              void* d_out, int out_size, void* d_ws,
                              size_t ws_size, hipStream_t stream) {
  const float* x = (const float*)d_in[0];
  const float* A_m = (const float*)d_in[1];
  const float* A_r = (const float*)d_in[2];
  const float* Bp = (const float*)d_in[3];
  const float* W_m = (const float*)d_in[4];
  const float* W_r = (const float*)d_in[5];
  const float* W_b = (const float*)d_in[6];
  const float* s_a = (const float*)d_in[7];
  const float* s_b = (const float*)d_in[8];
  const float* dyn_gamma = (const float*)d_in[9];
  const float* norm_gamma = (const float*)d_in[10];
  const float* norm_beta = (const float*)d_in[11];
  const float* Wblk = (const float*)d_in[12];
  const float* bblk = (const float*)d_in[13];
  float* out = (float*)d_out;

  char* ws = (char*)d_ws;
  short* Hst = (short*)(ws);                      // [0, 64 MiB)
  short* hbuf = (short*)(ws + 67108864);          // [64, 80) unnormalized h
  short* h2 = (short*)(ws + 83886080);            // [80, 96)
  char* aux = ws + 100663296;                     // [96 MiB, ...)
  short* gwm = (short*)(aux);                     // 16 KiB
  short* gwr = (short*)(aux + 16384);             // 64 KiB
  short* gwb = (short*)(aux + 16384 + 65536);     // 64 KiB
  float* rb = (float*)(aux + 16384 + 131072);     // 32 KiB
  float* S0w = (float*)(aux + 16384 + 131072 + 32768);
  float* T0d = (float*)(aux + 16384 + 131072 + 32768 + 128);
  f32x2* tst = (f32x2*)(aux + 16384 + 131072 + 32768 + 256);  // 32 KiB
  float* E0 = (float*)(aux + 16384 + 131072 + 32768 + 256 + 32768);  // 32 KiB
  float* E1 = E0 + LL * DD;                                          // 32 KiB
  // Wt lives in d_out: recomputed every call, overwritten by depth_last
  short* Wt = (short*)d_out;

  dim3 tb(256);
  prep_pack<<<32, tb, 0, stream>>>(W_m, W_r, W_b, dyn_gamma, norm_gamma,
                                   norm_beta, gwm, gwr, gwb, rb);
  prep_sums<<<4, dim3(64), 0, stream>>>(W_m, W_r, W_b, dyn_gamma, S0w, T0d);
  transpose_wblk<<<dim3(32, 32, 4), tb, 0, stream>>>(Wblk, norm_gamma, Wt);
  row_sums<<<dim3(512, 4), tb, 0, stream>>>(Wt, rb, bblk, E0, E1);
  width0_kernel<<<1024, tb, 0, stream>>>(x, Hst, hbuf, tst, A_m, A_r, gwm,
                                         gwr, s_a, S0w);
  for (int i = 0; i < LL; i++) {
    gemm_kernel<<<512, dim3(512), 0, stream>>>(
        hbuf, Wt + (size_t)i * DD * DD, tst, E0 + i * DD, E1 + i * DD, h2);
    if (i < LL - 1)
      fused_dw<<<1024, tb, 0, stream>>>(h2, Hst, hbuf, tst, Bp, gwb, s_b, A_m,
                                        A_r, gwm, gwr, s_a, S0w, T0d, i);
    else
      depth_last<<<1024, tb, 0, stream>>>(h2, Hst, out, Bp, gwb, s_b, T0d, i);
  }
}